// Round 4
// baseline (1927.285 us; speedup 1.0000x reference)
//
#include <hip/hip_runtime.h>
#include <hip/hip_bf16.h>

#define BB 64
#define TT 1536
#define FF 512
#define TP 256
#define UU 256
#define GG 1024
#define NC 250

typedef _Float16 h2_t __attribute__((ext_vector_type(2)));
typedef _Float16 f16x8 __attribute__((ext_vector_type(8)));
typedef float f32x4 __attribute__((ext_vector_type(4)));

#if defined(__has_builtin)
#  if __has_builtin(__builtin_amdgcn_fdot2)
#    define FDOT2(a, b, c) __builtin_amdgcn_fdot2((a), (b), (c), false)
#  endif
#endif
#ifndef FDOT2
__device__ __forceinline__ float fdot2_fb(h2_t a, h2_t b, float c) {
    return c + (float)a[0] * (float)b[0] + (float)a[1] * (float)b[1];
}
#  define FDOT2(a, b, c) fdot2_fb((a), (b), (c))
#endif

#define BC(u) __builtin_bit_cast(h2_t, (u))

__device__ __forceinline__ float hsig(float z) {
    return fminf(fmaxf(fmaf(z, 0.2f, 0.5f), 0.0f), 1.0f);
}

__device__ __forceinline__ float ftanh(float x) {
    float ax = fabsf(x);
    float e = __expf(-2.0f * ax);
    float t = (1.0f - e) / (1.0f + e);
    return copysignf(t, x);
}

__device__ __forceinline__ void dot4(float& z, const uint4& r, const uint4& h) {
    z = FDOT2(BC(r.x), BC(h.x), z);
    z = FDOT2(BC(r.y), BC(h.y), z);
    z = FDOT2(BC(r.z), BC(h.z), z);
    z = FDOT2(BC(r.w), BC(h.w), z);
}

// pair swap via DPP quad_perm [1,0,3,2] (VALU pipe, no LDS)
#if defined(__has_builtin) && __has_builtin(__builtin_amdgcn_mov_dpp)
template <int CTRL>
__device__ __forceinline__ float qperm(float v) {
    return __builtin_bit_cast(float,
        __builtin_amdgcn_mov_dpp(__builtin_bit_cast(int, v), CTRL, 0xf, 0xf, true));
}
#else
template <int CTRL>
__device__ __forceinline__ float qperm(float v) {
    return __shfl_xor(v, CTRL == 0xB1 ? 1 : 2, 64);
}
#endif

// keep a loaded quad alive in ARCH VGPRs (defeats AGPR-split / remat / sinking)
#define PIN4(q) asm volatile("" : "+v"((q).x), "+v"((q).y), "+v"((q).z), "+v"((q).w))

// ---------------------------------------------------------------------------
// Kernel 1: AveragePooling1D(6). x[64,1536,512] f32 -> xph[64,256,512] f16.
// ---------------------------------------------------------------------------
__global__ __launch_bounds__(256) void pool_kernel(const float* __restrict__ x,
                                                   _Float16* __restrict__ xph) {
    int idx = blockIdx.x * 256 + threadIdx.x;   // [0, 2097152)
    int f4 = (idx & 127) << 2;
    int m = idx >> 7;                           // b*256 + tp
    int tp = m & (TP - 1);
    int b = m >> 8;
    const float* src = x + ((size_t)b * TT + (size_t)tp * 6) * FF + f4;
    float sx = 0.f, sy = 0.f, sz = 0.f, sw = 0.f;
#pragma unroll
    for (int j = 0; j < 6; ++j) {
        float4 v = *(const float4*)&src[j * FF];
        sx += v.x; sy += v.y; sz += v.z; sw += v.w;
    }
    const float r6 = 1.0f / 6.0f;
    h2_t lo, hi;
    lo[0] = (_Float16)(sx * r6); lo[1] = (_Float16)(sy * r6);
    hi[0] = (_Float16)(sz * r6); hi[1] = (_Float16)(sw * r6);
    float2 w = make_float2(__builtin_bit_cast(float, lo), __builtin_bit_cast(float, hi));
    *(float2*)&xph[(size_t)m * FF + f4] = w;
}

// ---------------------------------------------------------------------------
// Kernel 2: tiled transpose + f32->f16 convert. in f32 [K][N] -> out f16 [N][K].
// PERM=1 additionally permutes out row: n=(g*256+u) -> u*4+g (gate-major -> unit-major).
// ---------------------------------------------------------------------------
template <int PERM>
__global__ __launch_bounds__(256) void transpose_cvt(const float* __restrict__ in,
                                                     _Float16* __restrict__ out,
                                                     int K, int N) {
    __shared__ _Float16 tile[32][42];
    const int r = threadIdx.x >> 3;          // 0..31
    const int c4 = (threadIdx.x & 7) << 2;   // 0,4,..,28
    const int n0 = blockIdx.x << 5;
    const int k0 = blockIdx.y << 5;
    float4 v = *(const float4*)&in[(size_t)(k0 + r) * N + n0 + c4];
    tile[r][c4 + 0] = (_Float16)v.x;
    tile[r][c4 + 1] = (_Float16)v.y;
    tile[r][c4 + 2] = (_Float16)v.z;
    tile[r][c4 + 3] = (_Float16)v.w;
    __syncthreads();
    int n = n0 + r;
    int orow = PERM ? (((n & 255) << 2) | (n >> 8)) : n;
    h2_t lo, hi;
    lo[0] = tile[c4 + 0][r]; lo[1] = tile[c4 + 1][r];
    hi[0] = tile[c4 + 2][r]; hi[1] = tile[c4 + 3][r];
    float2 w = make_float2(__builtin_bit_cast(float, lo), __builtin_bit_cast(float, hi));
    *(float2*)&out[(size_t)orow * K + k0 + c4] = w;
}

// ---------------------------------------------------------------------------
// Kernel 2b: Rt f16 [1024][256] -> Rq uint4 [64][512] (quad-major, thread-minor).
// Quad q=(g*16+kk), thread t (u=t>>1, s=t&1): 8 f16 of R[128s+8kk .. +7][g*256+u]
// = contiguous Rt[(g*256+u)*256 + 128s+8kk .. +7]. Writes perfectly coalesced.
// ---------------------------------------------------------------------------
__global__ __launch_bounds__(256) void conv_rq(const _Float16* __restrict__ Rt,
                                               uint4* __restrict__ Rq) {
    int d = blockIdx.x * 256 + threadIdx.x;   // [0, 32768)
    int q = d >> 9, t = d & 511;
    int g = q >> 4, kk = q & 15;
    int u = t >> 1, s = t & 1;
    int c = (g << 8) | u;
    int k0 = (s << 7) | (kk << 3);
    Rq[d] = *(const uint4*)&Rt[(size_t)c * 256 + k0];
}

// ---------------------------------------------------------------------------
// Kernel 3: zx = xph @ W + b via f16 MFMA 16x16x32. M=16384,N=1024,K=512.
// ---------------------------------------------------------------------------
__global__ __launch_bounds__(256, 2) void gemm_zx_mfma(const _Float16* __restrict__ Ah,
                                                       const _Float16* __restrict__ Bt,
                                                       const float* __restrict__ bias,
                                                       float* __restrict__ C) {
    __shared__ _Float16 As[128 * 40];
    __shared__ _Float16 Bs[128 * 40];
    const int tid = threadIdx.x;
    const int bn = blockIdx.x * 128;
    const int bm = blockIdx.y * 128;
    const int wave = tid >> 6, lane = tid & 63;
    const int wm = (wave & 1) * 64, wn = (wave >> 1) * 64;
    const int l15 = lane & 15, q8 = (lane >> 4) * 8;
    const int srow = tid >> 1, shalf = tid & 1;

    f32x4 acc[4][4] = {};
    const uint4* ag = (const uint4*)(Ah + (size_t)(bm + srow) * FF);
    const uint4* bg = (const uint4*)(Bt + (size_t)(bn + srow) * FF);
    uint4* as_st = (uint4*)As + 5 * srow + 2 * shalf;
    uint4* bs_st = (uint4*)Bs + 5 * srow + 2 * shalf;

    for (int k0 = 0; k0 < FF; k0 += 32) {
        int qi = (k0 >> 3) + shalf * 2;
        uint4 a0 = ag[qi], a1 = ag[qi + 1];
        uint4 b0 = bg[qi], b1 = bg[qi + 1];
        __syncthreads();
        as_st[0] = a0; as_st[1] = a1;
        bs_st[0] = b0; bs_st[1] = b1;
        __syncthreads();
        f16x8 af[4], bf[4];
#pragma unroll
        for (int mt = 0; mt < 4; ++mt)
            af[mt] = *(const f16x8*)&As[(wm + 16 * mt + l15) * 40 + q8];
#pragma unroll
        for (int nt = 0; nt < 4; ++nt)
            bf[nt] = *(const f16x8*)&Bs[(wn + 16 * nt + l15) * 40 + q8];
#pragma unroll
        for (int mt = 0; mt < 4; ++mt)
#pragma unroll
            for (int nt = 0; nt < 4; ++nt)
                acc[mt][nt] = __builtin_amdgcn_mfma_f32_16x16x32_f16(af[mt], bf[nt],
                                                                    acc[mt][nt], 0, 0, 0);
    }
    const int rq = (lane >> 4) * 4;
#pragma unroll
    for (int nt = 0; nt < 4; ++nt) {
        int col = bn + wn + 16 * nt + l15;            // permuted col' = u*4+g
        int oc = ((col & 3) << 8) | (col >> 2);       // original col = g*256+u
        float bv = bias[oc];
#pragma unroll
        for (int mt = 0; mt < 4; ++mt) {
#pragma unroll
            for (int r = 0; r < 4; ++r) {
                int row = bm + wm + 16 * mt + rq + r;
                C[(size_t)row * GG + col] = ((const float*)&acc[mt][nt])[r] + bv;
            }
        }
    }
}

// ---------------------------------------------------------------------------
// Kernel 4: LSTM scan. 64 WGs (one per batch), 512 threads.
// Thread t: unit u=t>>1 (all 4 gates), K-half s=t&1 (k in [128s,128s+128)).
// R = 64 quads/thread, split:
//   - even kk (32 quads, 128 regs): loaded once, PINNED in arch VGPRs (PIN4).
//   - odd  kk (32 quads): re-streamed from L2 every step (R is step-invariant;
//     Rq = 512 KB, resident in every XCD L2). Rolling issue, lead 5 positions,
//     wrapping across the step boundary -> <=3 targets (48 regs) in flight.
// LDS holds ONLY h (16 broadcast ds_read_b128/thread/step, ~1 KB).
// One DPP pair-swap reduces K; gates computed redundantly by the lane pair.
// One barrier/step via double-buffered h.
// ---------------------------------------------------------------------------
__global__ __launch_bounds__(512)
__attribute__((amdgpu_waves_per_eu(2)))
void lstm_scan(const float* __restrict__ zx,
               const uint4* __restrict__ Rq,
               float* __restrict__ hfin) {
    __shared__ __align__(16) _Float16 hbuf[2][2][136];  // [buf][s][128+8 pad]
    const int b = blockIdx.x;
    const int t = threadIdx.x;
    const int u = t >> 1, s = t & 1;

    const uint4* rqt = Rq + t;   // quad (g,kk) at rqt[(g*16+kk)*512]

    // pinned: even kk
    uint4 rv[4][8];
#pragma unroll
    for (int g = 0; g < 4; ++g)
#pragma unroll
        for (int e = 0; e < 8; ++e)
            rv[g][e] = rqt[(size_t)(g * 16 + 2 * e) * 512];
#pragma unroll
    for (int g = 0; g < 4; ++g)
#pragma unroll
        for (int e = 0; e < 8; ++e)
            PIN4(rv[g][e]);

    // streamed ring buffers; slot = tgt>>1. Prologue issues step-0's tgt 1,3.
    uint4 stb[8][4];
#pragma unroll
    for (int g = 0; g < 4; ++g) stb[0][g] = rqt[(size_t)(g * 16 + 1) * 512];
#pragma unroll
    for (int g = 0; g < 4; ++g) stb[1][g] = rqt[(size_t)(g * 16 + 3) * 512];

    if (t < 272) ((unsigned*)hbuf)[t] = 0u;   // zero both h buffers (1088 B)
    float c = 0.0f;
    const float4* zxp = (const float4*)zx + (size_t)b * TP * UU + u;  // +UU per step
    float4 zn = zxp[0];
    __syncthreads();

#pragma unroll 1
    for (int step = 0; step < TP; ++step) {
        float4 zn2 = zxp[(size_t)((step + 1 < TP) ? step + 1 : step) * UU];
        const uint4* hq = (const uint4*)hbuf[step & 1][s];
        float z[4] = {0.f, 0.f, 0.f, 0.f};
#pragma unroll
        for (int kk = 0; kk < 16; ++kk) {
            if ((kk & 1) == 0) {
                // rolling issue: target = (kk+5)&15 (odd); kk=12,14 feed NEXT step
                const int tgt = (kk + 5) & 15;
#pragma unroll
                for (int g = 0; g < 4; ++g)
                    stb[tgt >> 1][g] = rqt[(size_t)(g * 16 + tgt) * 512];
            }
            uint4 hh = hq[kk];   // broadcast read (2 addrs/wave, disjoint banks)
            if (kk & 1) {
#pragma unroll
                for (int g = 0; g < 4; ++g) dot4(z[g], stb[kk >> 1][g], hh);
            } else {
#pragma unroll
                for (int g = 0; g < 4; ++g) dot4(z[g], rv[g][kk >> 1], hh);
            }
        }
        // single pair-swap completes the K reduction; both lanes get full sums
#pragma unroll
        for (int g = 0; g < 4; ++g) z[g] += qperm<0xB1>(z[g]);

        float ig = hsig(z[0] + zn.x);
        float fg = hsig(z[1] + zn.y);
        float gv = ftanh(z[2] + zn.z);
        float og = hsig(z[3] + zn.w);
        c = fmaf(fg, c, ig * gv);
        float h = og * ftanh(c);
        if (s == 0) {
            hbuf[(step + 1) & 1][u >> 7][u & 127] = (_Float16)h;
            if (step == TP - 1) hfin[(size_t)b * UU + u] = h;
        }
        zn = zn2;
        __syncthreads();   // one barrier per step (write buf != read buf)
    }
}

// ---------------------------------------------------------------------------
// Kernel 5: logits = h @ Wd + bd; softmax. One WG per batch row.
// ---------------------------------------------------------------------------
__global__ __launch_bounds__(256) void dense_softmax(const float* __restrict__ hfin,
                                                     const float* __restrict__ Wd,
                                                     const float* __restrict__ bd,
                                                     float* __restrict__ out) {
    __shared__ __align__(16) float hbuf[UU];
    __shared__ float red[256];
    const int b = blockIdx.x;
    const int tid = threadIdx.x;
    hbuf[tid] = hfin[(size_t)b * UU + tid];
    __syncthreads();
    float logit = -3.0e38f;
    if (tid < NC) {
        float acc = bd[tid];
        for (int u = 0; u < UU; u += 4) {
            float4 hv = *(const float4*)&hbuf[u];
            acc = fmaf(hv.x, Wd[(size_t)(u + 0) * NC + tid], acc);
            acc = fmaf(hv.y, Wd[(size_t)(u + 1) * NC + tid], acc);
            acc = fmaf(hv.z, Wd[(size_t)(u + 2) * NC + tid], acc);
            acc = fmaf(hv.w, Wd[(size_t)(u + 3) * NC + tid], acc);
        }
        logit = acc;
    }
    red[tid] = logit;
    __syncthreads();
    for (int sdx = 128; sdx > 0; sdx >>= 1) {
        if (tid < sdx) red[tid] = fmaxf(red[tid], red[tid + sdx]);
        __syncthreads();
    }
    float mx = red[0];
    __syncthreads();
    float e = (tid < NC) ? expf(logit - mx) : 0.0f;
    red[tid] = e;
    __syncthreads();
    for (int sdx = 128; sdx > 0; sdx >>= 1) {
        if (tid < sdx) red[tid] += red[tid + sdx];
        __syncthreads();
    }
    if (tid < NC) out[(size_t)b * NC + tid] = e / red[0];
}

// ---------------------------------------------------------------------------
extern "C" void kernel_launch(void* const* d_in, const int* in_sizes, int n_in,
                              void* d_out, int out_size, void* d_ws, size_t ws_size,
                              hipStream_t stream) {
    const float* x  = (const float*)d_in[0];
    const float* W  = (const float*)d_in[1];
    const float* R  = (const float*)d_in[2];
    const float* bv = (const float*)d_in[3];
    const float* Wd = (const float*)d_in[4];
    const float* bd = (const float*)d_in[5];
    float* out = (float*)d_out;

    char* ws = (char*)d_ws;
    _Float16* xph = (_Float16*)ws;                         // 16 MB
    float* zx = (float*)(ws + 16777216);                   // 64 MB
    _Float16* Rt = (_Float16*)(ws + 16777216);             // 512 KB, aliases zx
                                                           // (dead before GEMM writes zx)
    _Float16* Wtp = (_Float16*)(ws + 83886080);            // 1 MB  (permuted W^T f16)
    uint4* Rq = (uint4*)(ws + 84934656);                   // 512 KB ([quad][thread])
    float* hfin = (float*)(ws + 85458944);                 // 64 KB

    hipLaunchKernelGGL(pool_kernel, dim3(8192), dim3(256), 0, stream, x, xph);
    hipLaunchKernelGGL(HIP_KERNEL_NAME(transpose_cvt<1>), dim3(32, 16), dim3(256), 0,
                       stream, W, Wtp, FF, GG);
    hipLaunchKernelGGL(HIP_KERNEL_NAME(transpose_cvt<0>), dim3(32, 8), dim3(256), 0,
                       stream, R, Rt, UU, GG);
    hipLaunchKernelGGL(conv_rq, dim3(128), dim3(256), 0, stream, Rt, Rq);
    hipLaunchKernelGGL(gemm_zx_mfma, dim3(8, 128), dim3(256), 0, stream,
                       xph, Wtp, bv, zx);
    hipLaunchKernelGGL(lstm_scan, dim3(64), dim3(512), 0, stream, zx, Rq, hfin);
    hipLaunchKernelGGL(dense_softmax, dim3(64), dim3(256), 0, stream, hfin, Wd, bd, out);
}

// Round 5
// 805.766 us; speedup vs baseline: 2.3919x; 2.3919x over previous
//
#include <hip/hip_runtime.h>
#include <hip/hip_bf16.h>

#define BB 64
#define TT 1536
#define FF 512
#define TP 256
#define UU 256
#define GG 1024
#define NC 250

typedef _Float16 h2_t __attribute__((ext_vector_type(2)));
typedef _Float16 f16x8 __attribute__((ext_vector_type(8)));
typedef float f32x4 __attribute__((ext_vector_type(4)));

#if defined(__has_builtin)
#  if __has_builtin(__builtin_amdgcn_fdot2)
#    define FDOT2(a, b, c) __builtin_amdgcn_fdot2((a), (b), (c), false)
#  endif
#endif
#ifndef FDOT2
__device__ __forceinline__ float fdot2_fb(h2_t a, h2_t b, float c) {
    return c + (float)a[0] * (float)b[0] + (float)a[1] * (float)b[1];
}
#  define FDOT2(a, b, c) fdot2_fb((a), (b), (c))
#endif

#define BC(u) __builtin_bit_cast(h2_t, (u))

__device__ __forceinline__ float hsig(float z) {
    return fminf(fmaxf(fmaf(z, 0.2f, 0.5f), 0.0f), 1.0f);
}

__device__ __forceinline__ float ftanh(float x) {
    float ax = fabsf(x);
    float e = __expf(-2.0f * ax);
    float t = (1.0f - e) / (1.0f + e);
    return copysignf(t, x);
}

__device__ __forceinline__ void dot4(float& z, const uint4& r, const uint4& h) {
    z = FDOT2(BC(r.x), BC(h.x), z);
    z = FDOT2(BC(r.y), BC(h.y), z);
    z = FDOT2(BC(r.z), BC(h.z), z);
    z = FDOT2(BC(r.w), BC(h.w), z);
}

// quad all-reduce add via DPP quad_perm (VALU pipe, no LDS)
#if defined(__has_builtin) && __has_builtin(__builtin_amdgcn_mov_dpp)
template <int CTRL>
__device__ __forceinline__ float qperm(float v) {
    return __builtin_bit_cast(float,
        __builtin_amdgcn_mov_dpp(__builtin_bit_cast(int, v), CTRL, 0xf, 0xf, true));
}
#else
template <int CTRL>
__device__ __forceinline__ float qperm(float v) {
    return __shfl_xor(v, CTRL == 0xB1 ? 1 : 2, 64);
}
#endif

// ---------------------------------------------------------------------------
// Kernel 1: AveragePooling1D(6). x[64,1536,512] f32 -> xph[64,256,512] f16.
// ---------------------------------------------------------------------------
__global__ __launch_bounds__(256) void pool_kernel(const float* __restrict__ x,
                                                   _Float16* __restrict__ xph) {
    int idx = blockIdx.x * 256 + threadIdx.x;   // [0, 2097152)
    int f4 = (idx & 127) << 2;
    int m = idx >> 7;                           // b*256 + tp
    int tp = m & (TP - 1);
    int b = m >> 8;
    const float* src = x + ((size_t)b * TT + (size_t)tp * 6) * FF + f4;
    float sx = 0.f, sy = 0.f, sz = 0.f, sw = 0.f;
#pragma unroll
    for (int j = 0; j < 6; ++j) {
        float4 v = *(const float4*)&src[j * FF];
        sx += v.x; sy += v.y; sz += v.z; sw += v.w;
    }
    const float r6 = 1.0f / 6.0f;
    h2_t lo, hi;
    lo[0] = (_Float16)(sx * r6); lo[1] = (_Float16)(sy * r6);
    hi[0] = (_Float16)(sz * r6); hi[1] = (_Float16)(sw * r6);
    float2 w = make_float2(__builtin_bit_cast(float, lo), __builtin_bit_cast(float, hi));
    *(float2*)&xph[(size_t)m * FF + f4] = w;
}

// ---------------------------------------------------------------------------
// Kernel 2: tiled transpose + f32->f16 convert. in f32 [K][N] -> out f16 [N][K].
// PERM=1 additionally permutes out row: n=(g*256+u) -> u*4+g (gate-major -> unit-major).
// ---------------------------------------------------------------------------
template <int PERM>
__global__ __launch_bounds__(256) void transpose_cvt(const float* __restrict__ in,
                                                     _Float16* __restrict__ out,
                                                     int K, int N) {
    __shared__ _Float16 tile[32][42];
    const int r = threadIdx.x >> 3;          // 0..31
    const int c4 = (threadIdx.x & 7) << 2;   // 0,4,..,28
    const int n0 = blockIdx.x << 5;
    const int k0 = blockIdx.y << 5;
    float4 v = *(const float4*)&in[(size_t)(k0 + r) * N + n0 + c4];
    tile[r][c4 + 0] = (_Float16)v.x;
    tile[r][c4 + 1] = (_Float16)v.y;
    tile[r][c4 + 2] = (_Float16)v.z;
    tile[r][c4 + 3] = (_Float16)v.w;
    __syncthreads();
    int n = n0 + r;
    int orow = PERM ? (((n & 255) << 2) | (n >> 8)) : n;
    h2_t lo, hi;
    lo[0] = tile[c4 + 0][r]; lo[1] = tile[c4 + 1][r];
    hi[0] = tile[c4 + 2][r]; hi[1] = tile[c4 + 3][r];
    float2 w = make_float2(__builtin_bit_cast(float, lo), __builtin_bit_cast(float, hi));
    *(float2*)&out[(size_t)orow * K + k0 + c4] = w;
}

// ---------------------------------------------------------------------------
// Kernel 2b: Rt f16 [1024][256] -> Rq uint4 [32][1024] (quad-major, thread-minor)
// for the 4-way K-split scan. Quad q=(g*8+kk), thread t (u=t>>2, s=t&3):
// 8 f16 of R[64s+8kk .. +7][g*256+u] = contiguous Rt[(g*256+u)*256 + 64s+8kk].
// ---------------------------------------------------------------------------
__global__ __launch_bounds__(256) void conv_rq(const _Float16* __restrict__ Rt,
                                               uint4* __restrict__ Rq) {
    int d = blockIdx.x * 256 + threadIdx.x;   // [0, 32768)
    int q = d >> 10, t = d & 1023;
    int g = q >> 3, kk = q & 7;
    int u = t >> 2, s = t & 3;
    int col = (g << 8) | u;
    int k0 = (s << 6) | (kk << 3);
    Rq[d] = *(const uint4*)&Rt[(size_t)col * 256 + k0];
}

// ---------------------------------------------------------------------------
// Kernel 3: zx = xph @ W + b via f16 MFMA 16x16x32. M=16384,N=1024,K=512.
// ---------------------------------------------------------------------------
__global__ __launch_bounds__(256, 2) void gemm_zx_mfma(const _Float16* __restrict__ Ah,
                                                       const _Float16* __restrict__ Bt,
                                                       const float* __restrict__ bias,
                                                       float* __restrict__ C) {
    __shared__ _Float16 As[128 * 40];
    __shared__ _Float16 Bs[128 * 40];
    const int tid = threadIdx.x;
    const int bn = blockIdx.x * 128;
    const int bm = blockIdx.y * 128;
    const int wave = tid >> 6, lane = tid & 63;
    const int wm = (wave & 1) * 64, wn = (wave >> 1) * 64;
    const int l15 = lane & 15, q8 = (lane >> 4) * 8;
    const int srow = tid >> 1, shalf = tid & 1;

    f32x4 acc[4][4] = {};
    const uint4* ag = (const uint4*)(Ah + (size_t)(bm + srow) * FF);
    const uint4* bg = (const uint4*)(Bt + (size_t)(bn + srow) * FF);
    uint4* as_st = (uint4*)As + 5 * srow + 2 * shalf;
    uint4* bs_st = (uint4*)Bs + 5 * srow + 2 * shalf;

    for (int k0 = 0; k0 < FF; k0 += 32) {
        int qi = (k0 >> 3) + shalf * 2;
        uint4 a0 = ag[qi], a1 = ag[qi + 1];
        uint4 b0 = bg[qi], b1 = bg[qi + 1];
        __syncthreads();
        as_st[0] = a0; as_st[1] = a1;
        bs_st[0] = b0; bs_st[1] = b1;
        __syncthreads();
        f16x8 af[4], bf[4];
#pragma unroll
        for (int mt = 0; mt < 4; ++mt)
            af[mt] = *(const f16x8*)&As[(wm + 16 * mt + l15) * 40 + q8];
#pragma unroll
        for (int nt = 0; nt < 4; ++nt)
            bf[nt] = *(const f16x8*)&Bs[(wn + 16 * nt + l15) * 40 + q8];
#pragma unroll
        for (int mt = 0; mt < 4; ++mt)
#pragma unroll
            for (int nt = 0; nt < 4; ++nt)
                acc[mt][nt] = __builtin_amdgcn_mfma_f32_16x16x32_f16(af[mt], bf[nt],
                                                                    acc[mt][nt], 0, 0, 0);
    }
    const int rq = (lane >> 4) * 4;
#pragma unroll
    for (int nt = 0; nt < 4; ++nt) {
        int col = bn + wn + 16 * nt + l15;            // permuted col' = u*4+g
        int oc = ((col & 3) << 8) | (col >> 2);       // original col = g*256+u
        float bv = bias[oc];
#pragma unroll
        for (int mt = 0; mt < 4; ++mt) {
#pragma unroll
            for (int r = 0; r < 4; ++r) {
                int row = bm + wm + 16 * mt + rq + r;
                C[(size_t)row * GG + col] = ((const float*)&acc[mt][nt])[r] + bv;
            }
        }
    }
}

// ---------------------------------------------------------------------------
// Kernel 4: LSTM scan. 64 WGs (one per batch), 1024 threads (16 waves).
// Thread t: unit u=t>>2 (all 4 gates), K-quarter s=t&3 (k in [64s, 64s+64)).
// Per-thread R = 32 quads: 23 in arch VGPRs (92 dwords, fits the hard 128-reg
// cap for multi-wave WGs established in rounds 1-4) + 9 in LDS (147 KB).
// NO AGPR residency, NO streaming. 2-stage DPP quad butterfly reduces K;
// gates computed redundantly by the 4-lane quad; one barrier/step via
// double-buffered h. h quarters padded to 144 B -> 4 distinct bank groups.
// ---------------------------------------------------------------------------
__global__ __launch_bounds__(1024) void lstm_scan(const float* __restrict__ zx,
                                                  const uint4* __restrict__ Rq,
                                                  float* __restrict__ hfin) {
    __shared__ uint4 Rl[9][1024];                      // 147456 B
    __shared__ __align__(16) _Float16 hbuf[2][4][72];  // [buf][s][64+8 pad] = 1152 B
    const int b = blockIdx.x;
    const int t = threadIdx.x;
    const int u = t >> 2, s = t & 3;

    const uint4* rqt = Rq + t;   // quad (g,kk) at rqt[(g*8+kk)*1024]

    // reg quads: g0..g2 kk 0..5, g3 kk 0..4  (23 quads = 92 VGPRs)
    uint4 rv0[6], rv1[6], rv2[6], rv3[5];
#pragma unroll
    for (int kk = 0; kk < 6; ++kk) {
        rv0[kk] = rqt[(0 * 8 + kk) * 1024];
        rv1[kk] = rqt[(1 * 8 + kk) * 1024];
        rv2[kk] = rqt[(2 * 8 + kk) * 1024];
        if (kk < 5) rv3[kk] = rqt[(3 * 8 + kk) * 1024];
    }
    // LDS quads: g0k6 g0k7 g1k6 g1k7 g2k6 g2k7 g3k5 g3k6 g3k7
    Rl[0][t] = rqt[(0 * 8 + 6) * 1024];
    Rl[1][t] = rqt[(0 * 8 + 7) * 1024];
    Rl[2][t] = rqt[(1 * 8 + 6) * 1024];
    Rl[3][t] = rqt[(1 * 8 + 7) * 1024];
    Rl[4][t] = rqt[(2 * 8 + 6) * 1024];
    Rl[5][t] = rqt[(2 * 8 + 7) * 1024];
    Rl[6][t] = rqt[(3 * 8 + 5) * 1024];
    Rl[7][t] = rqt[(3 * 8 + 6) * 1024];
    Rl[8][t] = rqt[(3 * 8 + 7) * 1024];

    if (t < 288) ((unsigned*)hbuf)[t] = 0u;   // zero both h buffers (1152 B)
    float c = 0.0f;
    const float4* zxp = (const float4*)zx + (size_t)b * TP * UU + u;  // +UU per step
    float4 zn = zxp[0];
    __syncthreads();

#pragma unroll 1
    for (int step = 0; step < TP; ++step) {
        // prefetch next step's zx (covers HBM/L3 latency under this step's dots)
        float4 zn2 = zxp[(size_t)((step + 1 < TP) ? step + 1 : step) * UU];
        const char* hbase = (const char*)hbuf[step & 1] + s * 144;
        float z0 = 0.f, z1 = 0.f, z2 = 0.f, z3 = 0.f;
#pragma unroll
        for (int kk = 0; kk < 8; ++kk) {
            uint4 hh = *(const uint4*)(hbase + kk * 16);  // 4 addrs/wave, 4 bank groups
            if (kk < 6) dot4(z0, rv0[kk], hh); else dot4(z0, Rl[kk - 6][t], hh);
            if (kk < 6) dot4(z1, rv1[kk], hh); else dot4(z1, Rl[2 + kk - 6][t], hh);
            if (kk < 6) dot4(z2, rv2[kk], hh); else dot4(z2, Rl[4 + kk - 6][t], hh);
            if (kk < 5) dot4(z3, rv3[kk], hh); else dot4(z3, Rl[6 + kk - 5][t], hh);
        }
        // 2-stage quad butterfly: all 4 lanes get the full K sum
        z0 += qperm<0xB1>(z0); z0 += qperm<0x4E>(z0);
        z1 += qperm<0xB1>(z1); z1 += qperm<0x4E>(z1);
        z2 += qperm<0xB1>(z2); z2 += qperm<0x4E>(z2);
        z3 += qperm<0xB1>(z3); z3 += qperm<0x4E>(z3);

        float ig = hsig(z0 + zn.x);
        float fg = hsig(z1 + zn.y);
        float gv = ftanh(z2 + zn.z);
        float og = hsig(z3 + zn.w);
        c = fmaf(fg, c, ig * gv);
        float h = og * ftanh(c);
        if (s == 0) {
            hbuf[(step + 1) & 1][u >> 6][u & 63] = (_Float16)h;
            if (step == TP - 1) hfin[(size_t)b * UU + u] = h;
        }
        zn = zn2;
        __syncthreads();   // one barrier per step (write buf != read buf)
    }
}

// ---------------------------------------------------------------------------
// Kernel 5: logits = h @ Wd + bd; softmax. One WG per batch row.
// ---------------------------------------------------------------------------
__global__ __launch_bounds__(256) void dense_softmax(const float* __restrict__ hfin,
                                                     const float* __restrict__ Wd,
                                                     const float* __restrict__ bd,
                                                     float* __restrict__ out) {
    __shared__ __align__(16) float hbuf[UU];
    __shared__ float red[256];
    const int b = blockIdx.x;
    const int tid = threadIdx.x;
    hbuf[tid] = hfin[(size_t)b * UU + tid];
    __syncthreads();
    float logit = -3.0e38f;
    if (tid < NC) {
        float acc = bd[tid];
        for (int u = 0; u < UU; u += 4) {
            float4 hv = *(const float4*)&hbuf[u];
            acc = fmaf(hv.x, Wd[(size_t)(u + 0) * NC + tid], acc);
            acc = fmaf(hv.y, Wd[(size_t)(u + 1) * NC + tid], acc);
            acc = fmaf(hv.z, Wd[(size_t)(u + 2) * NC + tid], acc);
            acc = fmaf(hv.w, Wd[(size_t)(u + 3) * NC + tid], acc);
        }
        logit = acc;
    }
    red[tid] = logit;
    __syncthreads();
    for (int sdx = 128; sdx > 0; sdx >>= 1) {
        if (tid < sdx) red[tid] = fmaxf(red[tid], red[tid + sdx]);
        __syncthreads();
    }
    float mx = red[0];
    __syncthreads();
    float e = (tid < NC) ? expf(logit - mx) : 0.0f;
    red[tid] = e;
    __syncthreads();
    for (int sdx = 128; sdx > 0; sdx >>= 1) {
        if (tid < sdx) red[tid] += red[tid + sdx];
        __syncthreads();
    }
    if (tid < NC) out[(size_t)b * NC + tid] = e / red[0];
}

// ---------------------------------------------------------------------------
extern "C" void kernel_launch(void* const* d_in, const int* in_sizes, int n_in,
                              void* d_out, int out_size, void* d_ws, size_t ws_size,
                              hipStream_t stream) {
    const float* x  = (const float*)d_in[0];
    const float* W  = (const float*)d_in[1];
    const float* R  = (const float*)d_in[2];
    const float* bv = (const float*)d_in[3];
    const float* Wd = (const float*)d_in[4];
    const float* bd = (const float*)d_in[5];
    float* out = (float*)d_out;

    char* ws = (char*)d_ws;
    _Float16* xph = (_Float16*)ws;                         // 16 MB
    float* zx = (float*)(ws + 16777216);                   // 64 MB
    _Float16* Rt = (_Float16*)(ws + 16777216);             // 512 KB, aliases zx
                                                           // (dead before GEMM writes zx)
    _Float16* Wtp = (_Float16*)(ws + 83886080);            // 1 MB  (permuted W^T f16)
    uint4* Rq = (uint4*)(ws + 84934656);                   // 512 KB ([quad][thread])
    float* hfin = (float*)(ws + 85458944);                 // 64 KB

    hipLaunchKernelGGL(pool_kernel, dim3(8192), dim3(256), 0, stream, x, xph);
    hipLaunchKernelGGL(HIP_KERNEL_NAME(transpose_cvt<1>), dim3(32, 16), dim3(256), 0,
                       stream, W, Wtp, FF, GG);
    hipLaunchKernelGGL(HIP_KERNEL_NAME(transpose_cvt<0>), dim3(32, 8), dim3(256), 0,
                       stream, R, Rt, UU, GG);
    hipLaunchKernelGGL(conv_rq, dim3(128), dim3(256), 0, stream, Rt, Rq);
    hipLaunchKernelGGL(gemm_zx_mfma, dim3(8, 128), dim3(256), 0, stream,
                       xph, Wtp, bv, zx);
    hipLaunchKernelGGL(lstm_scan, dim3(64), dim3(1024), 0, stream, zx, Rq, hfin);
    hipLaunchKernelGGL(dense_softmax, dim3(64), dim3(256), 0, stream, hfin, Wd, bd, out);
}

// Round 6
// 720.215 us; speedup vs baseline: 2.6760x; 1.1188x over previous
//
#include <hip/hip_runtime.h>
#include <hip/hip_bf16.h>

#define BB 64
#define TT 1536
#define FF 512
#define TP 256
#define UU 256
#define GG 1024
#define NC 250

typedef _Float16 h2_t __attribute__((ext_vector_type(2)));
typedef _Float16 f16x8 __attribute__((ext_vector_type(8)));
typedef float f32x4 __attribute__((ext_vector_type(4)));

#if defined(__has_builtin)
#  if __has_builtin(__builtin_amdgcn_fdot2)
#    define FDOT2(a, b, c) __builtin_amdgcn_fdot2((a), (b), (c), false)
#  endif
#endif
#ifndef FDOT2
__device__ __forceinline__ float fdot2_fb(h2_t a, h2_t b, float c) {
    return c + (float)a[0] * (float)b[0] + (float)a[1] * (float)b[1];
}
#  define FDOT2(a, b, c) fdot2_fb((a), (b), (c))
#endif

#define BC(u) __builtin_bit_cast(h2_t, (u))

__device__ __forceinline__ float hsig(float z) {
    return fminf(fmaxf(fmaf(z, 0.2f, 0.5f), 0.0f), 1.0f);
}

__device__ __forceinline__ float ftanh(float x) {
    float ax = fabsf(x);
    float e = __expf(-2.0f * ax);
    float t = (1.0f - e) / (1.0f + e);
    return copysignf(t, x);
}

__device__ __forceinline__ void dot4(float& z, const uint4& r, const uint4& h) {
    z = FDOT2(BC(r.x), BC(h.x), z);
    z = FDOT2(BC(r.y), BC(h.y), z);
    z = FDOT2(BC(r.z), BC(h.z), z);
    z = FDOT2(BC(r.w), BC(h.w), z);
}

// lane swaps via DPP quad_perm (VALU pipe, no LDS). 0xB1 = lane^1, 0x4E = lane^2.
#if defined(__has_builtin) && __has_builtin(__builtin_amdgcn_mov_dpp)
template <int CTRL>
__device__ __forceinline__ float qperm(float v) {
    return __builtin_bit_cast(float,
        __builtin_amdgcn_mov_dpp(__builtin_bit_cast(int, v), CTRL, 0xf, 0xf, true));
}
__device__ __forceinline__ unsigned uswap2(unsigned v) {
    return (unsigned)__builtin_amdgcn_mov_dpp((int)v, 0x4E, 0xf, 0xf, true);
}
#else
template <int CTRL>
__device__ __forceinline__ float qperm(float v) {
    return __shfl_xor(v, CTRL == 0xB1 ? 1 : 2, 64);
}
__device__ __forceinline__ unsigned uswap2(unsigned v) { return __shfl_xor(v, 2, 64); }
#endif

__device__ __forceinline__ uint4 swap2_quad(uint4 v) {
    uint4 r;
    r.x = uswap2(v.x); r.y = uswap2(v.y); r.z = uswap2(v.z); r.w = uswap2(v.w);
    return r;
}

// ---------------------------------------------------------------------------
// Kernel 1: AveragePooling1D(6). x[64,1536,512] f32 -> xph[64,256,512] f16.
// ---------------------------------------------------------------------------
__global__ __launch_bounds__(256) void pool_kernel(const float* __restrict__ x,
                                                   _Float16* __restrict__ xph) {
    int idx = blockIdx.x * 256 + threadIdx.x;   // [0, 2097152)
    int f4 = (idx & 127) << 2;
    int m = idx >> 7;                           // b*256 + tp
    int tp = m & (TP - 1);
    int b = m >> 8;
    const float* src = x + ((size_t)b * TT + (size_t)tp * 6) * FF + f4;
    float sx = 0.f, sy = 0.f, sz = 0.f, sw = 0.f;
#pragma unroll
    for (int j = 0; j < 6; ++j) {
        float4 v = *(const float4*)&src[j * FF];
        sx += v.x; sy += v.y; sz += v.z; sw += v.w;
    }
    const float r6 = 1.0f / 6.0f;
    h2_t lo, hi;
    lo[0] = (_Float16)(sx * r6); lo[1] = (_Float16)(sy * r6);
    hi[0] = (_Float16)(sz * r6); hi[1] = (_Float16)(sw * r6);
    float2 w = make_float2(__builtin_bit_cast(float, lo), __builtin_bit_cast(float, hi));
    *(float2*)&xph[(size_t)m * FF + f4] = w;
}

// ---------------------------------------------------------------------------
// Kernel 2: tiled transpose + f32->f16 convert. in f32 [K][N] -> out f16 [N][K].
// PERM=1 additionally permutes out row: n=(g*256+u) -> u*4+g (gate-major -> unit-major).
// ---------------------------------------------------------------------------
template <int PERM>
__global__ __launch_bounds__(256) void transpose_cvt(const float* __restrict__ in,
                                                     _Float16* __restrict__ out,
                                                     int K, int N) {
    __shared__ _Float16 tile[32][42];
    const int r = threadIdx.x >> 3;          // 0..31
    const int c4 = (threadIdx.x & 7) << 2;   // 0,4,..,28
    const int n0 = blockIdx.x << 5;
    const int k0 = blockIdx.y << 5;
    float4 v = *(const float4*)&in[(size_t)(k0 + r) * N + n0 + c4];
    tile[r][c4 + 0] = (_Float16)v.x;
    tile[r][c4 + 1] = (_Float16)v.y;
    tile[r][c4 + 2] = (_Float16)v.z;
    tile[r][c4 + 3] = (_Float16)v.w;
    __syncthreads();
    int n = n0 + r;
    int orow = PERM ? (((n & 255) << 2) | (n >> 8)) : n;
    h2_t lo, hi;
    lo[0] = tile[c4 + 0][r]; lo[1] = tile[c4 + 1][r];
    hi[0] = tile[c4 + 2][r]; hi[1] = tile[c4 + 3][r];
    float2 w = make_float2(__builtin_bit_cast(float, lo), __builtin_bit_cast(float, hi));
    *(float2*)&out[(size_t)orow * K + k0 + c4] = w;
}

// ---------------------------------------------------------------------------
// Kernel 2b: Rt f16 [1024][256] -> Rq uint4 [64][512] (quad-major, thread-minor)
// for the 2-way K-split scan. Quad q=(g*16+kk), thread t (u=t>>1, s=t&1):
// 8 f16 of R[128s+8kk .. +7][g*256+u] = contiguous Rt[(g*256+u)*256 + 128s+8kk].
// (layout verified correct in rounds 3-4)
// ---------------------------------------------------------------------------
__global__ __launch_bounds__(256) void conv_rq(const _Float16* __restrict__ Rt,
                                               uint4* __restrict__ Rq) {
    int d = blockIdx.x * 256 + threadIdx.x;   // [0, 32768)
    int q = d >> 9, t = d & 511;
    int g = q >> 4, kk = q & 15;
    int u = t >> 1, s = t & 1;
    int col = (g << 8) | u;
    int k0 = (s << 7) | (kk << 3);
    Rq[d] = *(const uint4*)&Rt[(size_t)col * 256 + k0];
}

// ---------------------------------------------------------------------------
// Kernel 3: zx = xph @ W + b via f16 MFMA 16x16x32. M=16384,N=1024,K=512.
// ---------------------------------------------------------------------------
__global__ __launch_bounds__(256, 2) void gemm_zx_mfma(const _Float16* __restrict__ Ah,
                                                       const _Float16* __restrict__ Bt,
                                                       const float* __restrict__ bias,
                                                       float* __restrict__ C) {
    __shared__ _Float16 As[128 * 40];
    __shared__ _Float16 Bs[128 * 40];
    const int tid = threadIdx.x;
    const int bn = blockIdx.x * 128;
    const int bm = blockIdx.y * 128;
    const int wave = tid >> 6, lane = tid & 63;
    const int wm = (wave & 1) * 64, wn = (wave >> 1) * 64;
    const int l15 = lane & 15, q8 = (lane >> 4) * 8;
    const int srow = tid >> 1, shalf = tid & 1;

    f32x4 acc[4][4] = {};
    const uint4* ag = (const uint4*)(Ah + (size_t)(bm + srow) * FF);
    const uint4* bg = (const uint4*)(Bt + (size_t)(bn + srow) * FF);
    uint4* as_st = (uint4*)As + 5 * srow + 2 * shalf;
    uint4* bs_st = (uint4*)Bs + 5 * srow + 2 * shalf;

    for (int k0 = 0; k0 < FF; k0 += 32) {
        int qi = (k0 >> 3) + shalf * 2;
        uint4 a0 = ag[qi], a1 = ag[qi + 1];
        uint4 b0 = bg[qi], b1 = bg[qi + 1];
        __syncthreads();
        as_st[0] = a0; as_st[1] = a1;
        bs_st[0] = b0; bs_st[1] = b1;
        __syncthreads();
        f16x8 af[4], bf[4];
#pragma unroll
        for (int mt = 0; mt < 4; ++mt)
            af[mt] = *(const f16x8*)&As[(wm + 16 * mt + l15) * 40 + q8];
#pragma unroll
        for (int nt = 0; nt < 4; ++nt)
            bf[nt] = *(const f16x8*)&Bs[(wn + 16 * nt + l15) * 40 + q8];
#pragma unroll
        for (int mt = 0; mt < 4; ++mt)
#pragma unroll
            for (int nt = 0; nt < 4; ++nt)
                acc[mt][nt] = __builtin_amdgcn_mfma_f32_16x16x32_f16(af[mt], bf[nt],
                                                                    acc[mt][nt], 0, 0, 0);
    }
    const int rq = (lane >> 4) * 4;
#pragma unroll
    for (int nt = 0; nt < 4; ++nt) {
        int col = bn + wn + 16 * nt + l15;            // permuted col' = u*4+g
        int oc = ((col & 3) << 8) | (col >> 2);       // original col = g*256+u
        float bv = bias[oc];
#pragma unroll
        for (int mt = 0; mt < 4; ++mt) {
#pragma unroll
            for (int r = 0; r < 4; ++r) {
                int row = bm + wm + 16 * mt + rq + r;
                C[(size_t)row * GG + col] = ((const float*)&acc[mt][nt])[r] + bv;
            }
        }
    }
}

// ---------------------------------------------------------------------------
// Kernel 4: LSTM scan. 64 WGs (one per batch), 512 threads (8 waves).
// Thread t: unit u=t>>1 (all 4 gates), K-half s=t&1. Pipe-balanced design:
//   - LDS-instr diet (the measured bottleneck: b128 ~12cyc/instr/CU):
//     R: 52 quads "reg" (arch+AGPR; the allocator's half-split is accepted,
//     AGPR copy tax ~256cyc/wave < the LDS instrs it replaces) + 12 quads LDS.
//     h: 8 reads instead of 16 via DPP pair-exchange: lanes qs=u&1 read
//     different 16B h-quads in one ds_read_b128, swap via quad_perm(lane^2).
//     The qs-dependent quad order is folded into the R load (pre-swapped),
//     so no selects. LDS/step/CU: 272 -> ~168 instrs.
//   - h halves at 288B stride -> the 4 broadcast addr classes hit 4 disjoint
//     bank groups. One DPP pair-swap (lane^1) completes the K reduction.
//   - one barrier/step via double-buffered h.
// ---------------------------------------------------------------------------
__global__ __launch_bounds__(512) void lstm_scan(const float* __restrict__ zx,
                                                 const uint4* __restrict__ Rq,
                                                 float* __restrict__ hfin) {
    __shared__ uint4 Rl[12][512];                       // 98304 B
    __shared__ __align__(16) _Float16 hbuf[2][2][144];  // [buf][half][128+16 pad]
    const int b = blockIdx.x;
    const int t = threadIdx.x;
    const int u = t >> 1, s = t & 1, qs = u & 1;

    const uint4* rqt = Rq + t;   // quad (g,kk) at rqt[(g*16+kk)*512]

    // reg quads, qs-swapped pairing: E[j] = quad(2j+qs), O[j] = quad(2j+1-qs).
    // g0,g1: pairs j=0..6 (kk 0..13); g2,g3: pairs j=0..5 (kk 0..11). 52 quads.
    uint4 rE0[7], rO0[7], rE1[7], rO1[7], rE2[6], rO2[6], rE3[6], rO3[6];
#pragma unroll
    for (int j = 0; j < 7; ++j) {
        rE0[j] = rqt[(size_t)(0 * 16 + 2 * j + qs) * 512];
        rO0[j] = rqt[(size_t)(0 * 16 + 2 * j + 1 - qs) * 512];
        rE1[j] = rqt[(size_t)(1 * 16 + 2 * j + qs) * 512];
        rO1[j] = rqt[(size_t)(1 * 16 + 2 * j + 1 - qs) * 512];
        if (j < 6) {
            rE2[j] = rqt[(size_t)(2 * 16 + 2 * j + qs) * 512];
            rO2[j] = rqt[(size_t)(2 * 16 + 2 * j + 1 - qs) * 512];
            rE3[j] = rqt[(size_t)(3 * 16 + 2 * j + qs) * 512];
            rO3[j] = rqt[(size_t)(3 * 16 + 2 * j + 1 - qs) * 512];
        }
    }
    // LDS pairs (qs-swapped at store): [0,1]=g2 j6, [2,3]=g3 j6,
    // [4,5]=g0 j7, [6,7]=g1 j7, [8,9]=g2 j7, [10,11]=g3 j7.
    Rl[0][t]  = rqt[(size_t)(2 * 16 + 12 + qs) * 512];
    Rl[1][t]  = rqt[(size_t)(2 * 16 + 13 - qs) * 512];
    Rl[2][t]  = rqt[(size_t)(3 * 16 + 12 + qs) * 512];
    Rl[3][t]  = rqt[(size_t)(3 * 16 + 13 - qs) * 512];
    Rl[4][t]  = rqt[(size_t)(0 * 16 + 14 + qs) * 512];
    Rl[5][t]  = rqt[(size_t)(0 * 16 + 15 - qs) * 512];
    Rl[6][t]  = rqt[(size_t)(1 * 16 + 14 + qs) * 512];
    Rl[7][t]  = rqt[(size_t)(1 * 16 + 15 - qs) * 512];
    Rl[8][t]  = rqt[(size_t)(2 * 16 + 14 + qs) * 512];
    Rl[9][t]  = rqt[(size_t)(2 * 16 + 15 - qs) * 512];
    Rl[10][t] = rqt[(size_t)(3 * 16 + 14 + qs) * 512];
    Rl[11][t] = rqt[(size_t)(3 * 16 + 15 - qs) * 512];

    if (t < 288) ((unsigned*)hbuf)[t] = 0u;   // zero both h buffers (1152 B)
    float c = 0.0f;
    const float4* zxp = (const float4*)zx + (size_t)b * TP * UU + u;  // +UU per step
    float4 zn = zxp[0];
    __syncthreads();

#pragma unroll 1
    for (int step = 0; step < TP; ++step) {
        // prefetch next step's zx (covers HBM/L3 latency under this step's dots)
        float4 zn2 = zxp[(size_t)((step + 1 < TP) ? step + 1 : step) * UU];
        // base: this buf, this K-half, this lane's quad-parity
        const char* hb = (const char*)hbuf + (step & 1) * 576 + s * 288 + qs * 16;
        float z0 = 0.f, z1 = 0.f, z2 = 0.f, z3 = 0.f;
#pragma unroll
        for (int j = 0; j < 8; ++j) {
            uint4 ha = *(const uint4*)(hb + j * 32);   // quad (2j+qs)
            uint4 hx = swap2_quad(ha);                 // quad (2j+1-qs) via lane^2
            if (j < 6) {
                dot4(z0, rE0[j], ha); dot4(z0, rO0[j], hx);
                dot4(z1, rE1[j], ha); dot4(z1, rO1[j], hx);
                dot4(z2, rE2[j], ha); dot4(z2, rO2[j], hx);
                dot4(z3, rE3[j], ha); dot4(z3, rO3[j], hx);
            } else if (j == 6) {
                dot4(z0, rE0[6], ha);  dot4(z0, rO0[6], hx);
                dot4(z1, rE1[6], ha);  dot4(z1, rO1[6], hx);
                dot4(z2, Rl[0][t], ha); dot4(z2, Rl[1][t], hx);
                dot4(z3, Rl[2][t], ha); dot4(z3, Rl[3][t], hx);
            } else {
                dot4(z0, Rl[4][t], ha);  dot4(z0, Rl[5][t], hx);
                dot4(z1, Rl[6][t], ha);  dot4(z1, Rl[7][t], hx);
                dot4(z2, Rl[8][t], ha);  dot4(z2, Rl[9][t], hx);
                dot4(z3, Rl[10][t], ha); dot4(z3, Rl[11][t], hx);
            }
        }
        // single pair-swap (lane^1 = other K-half, same u) completes K reduction
        z0 += qperm<0xB1>(z0);
        z1 += qperm<0xB1>(z1);
        z2 += qperm<0xB1>(z2);
        z3 += qperm<0xB1>(z3);

        float ig = hsig(z0 + zn.x);
        float fg = hsig(z1 + zn.y);
        float gv = ftanh(z2 + zn.z);
        float og = hsig(z3 + zn.w);
        c = fmaf(fg, c, ig * gv);
        float h = og * ftanh(c);
        if (s == 0) {
            hbuf[(step + 1) & 1][u >> 7][u & 127] = (_Float16)h;
            if (step == TP - 1) hfin[(size_t)b * UU + u] = h;
        }
        zn = zn2;
        __syncthreads();   // one barrier per step (write buf != read buf)
    }
}

// ---------------------------------------------------------------------------
// Kernel 5: logits = h @ Wd + bd; softmax. One WG per batch row.
// ---------------------------------------------------------------------------
__global__ __launch_bounds__(256) void dense_softmax(const float* __restrict__ hfin,
                                                     const float* __restrict__ Wd,
                                                     const float* __restrict__ bd,
                                                     float* __restrict__ out) {
    __shared__ __align__(16) float hbuf[UU];
    __shared__ float red[256];
    const int b = blockIdx.x;
    const int tid = threadIdx.x;
    hbuf[tid] = hfin[(size_t)b * UU + tid];
    __syncthreads();
    float logit = -3.0e38f;
    if (tid < NC) {
        float acc = bd[tid];
        for (int u = 0; u < UU; u += 4) {
            float4 hv = *(const float4*)&hbuf[u];
            acc = fmaf(hv.x, Wd[(size_t)(u + 0) * NC + tid], acc);
            acc = fmaf(hv.y, Wd[(size_t)(u + 1) * NC + tid], acc);
            acc = fmaf(hv.z, Wd[(size_t)(u + 2) * NC + tid], acc);
            acc = fmaf(hv.w, Wd[(size_t)(u + 3) * NC + tid], acc);
        }
        logit = acc;
    }
    red[tid] = logit;
    __syncthreads();
    for (int sdx = 128; sdx > 0; sdx >>= 1) {
        if (tid < sdx) red[tid] = fmaxf(red[tid], red[tid + sdx]);
        __syncthreads();
    }
    float mx = red[0];
    __syncthreads();
    float e = (tid < NC) ? expf(logit - mx) : 0.0f;
    red[tid] = e;
    __syncthreads();
    for (int sdx = 128; sdx > 0; sdx >>= 1) {
        if (tid < sdx) red[tid] += red[tid + sdx];
        __syncthreads();
    }
    if (tid < NC) out[(size_t)b * NC + tid] = e / red[0];
}

// ---------------------------------------------------------------------------
extern "C" void kernel_launch(void* const* d_in, const int* in_sizes, int n_in,
                              void* d_out, int out_size, void* d_ws, size_t ws_size,
                              hipStream_t stream) {
    const float* x  = (const float*)d_in[0];
    const float* W  = (const float*)d_in[1];
    const float* R  = (const float*)d_in[2];
    const float* bv = (const float*)d_in[3];
    const float* Wd = (const float*)d_in[4];
    const float* bd = (const float*)d_in[5];
    float* out = (float*)d_out;

    char* ws = (char*)d_ws;
    _Float16* xph = (_Float16*)ws;                         // 16 MB
    float* zx = (float*)(ws + 16777216);                   // 64 MB
    _Float16* Rt = (_Float16*)(ws + 16777216);             // 512 KB, aliases zx
                                                           // (dead before GEMM writes zx)
    _Float16* Wtp = (_Float16*)(ws + 83886080);            // 1 MB  (permuted W^T f16)
    uint4* Rq = (uint4*)(ws + 84934656);                   // 512 KB ([quad][thread])
    float* hfin = (float*)(ws + 85458944);                 // 64 KB

    hipLaunchKernelGGL(pool_kernel, dim3(8192), dim3(256), 0, stream, x, xph);
    hipLaunchKernelGGL(HIP_KERNEL_NAME(transpose_cvt<1>), dim3(32, 16), dim3(256), 0,
                       stream, W, Wtp, FF, GG);
    hipLaunchKernelGGL(HIP_KERNEL_NAME(transpose_cvt<0>), dim3(32, 8), dim3(256), 0,
                       stream, R, Rt, UU, GG);
    hipLaunchKernelGGL(conv_rq, dim3(128), dim3(256), 0, stream, Rt, Rq);
    hipLaunchKernelGGL(gemm_zx_mfma, dim3(8, 128), dim3(256), 0, stream,
                       xph, Wtp, bv, zx);
    hipLaunchKernelGGL(lstm_scan, dim3(64), dim3(512), 0, stream, zx, Rq, hfin);
    hipLaunchKernelGGL(dense_softmax, dim3(64), dim3(256), 0, stream, hfin, Wd, bd, out);
}